// Round 12
// baseline (526.638 us; speedup 1.0000x reference)
//
#include <hip/hip_runtime.h>
#include <hip/hip_bf16.h>
#include <cstdint>
#include <cstddef>

// Problem constants
#define TOKENS 4096       // B*T = 2*2048
#define CDIM   1024
#define HDIM   2730
#define HPAD2  2816       // HDIM padded to multiple of 128
#define NEXP   8
#define NPAIR  (TOKENS * 2)
#define NTB1   (HPAD2 / 128)   // 22 n-tiles for gemm1 (N-tile 128, dual)
#define NTB2   (CDIM / 128)    // 8 n-tiles for gemm2
#define NT1    (CDIM / 64)     // 16 K-steps gemm1
#define NT2H   (HPAD2 / 2 / 64) // 22 K-steps per K-half, gemm2
#define NCONV3 256             // conv_w3 tail chunks in gemm1 (32 rows each)

typedef __bf16 bf16_t;
typedef bf16_t bf16x8 __attribute__((ext_vector_type(8)));
typedef float  f32x4  __attribute__((ext_vector_type(4)));

// fp32 -> bf16, round-to-nearest-even
static __device__ __forceinline__ unsigned short f2bf(float f) {
    union { float f; unsigned int u; } v; v.f = f;
    unsigned int u = v.u;
    return (unsigned short)((u + 0x7FFFu + ((u >> 16) & 1u)) >> 16);
}
static __device__ __forceinline__ unsigned int pack2(float a, float b) {
    return (unsigned int)f2bf(a) | ((unsigned int)f2bf(b) << 16);
}

// async global->LDS, 16B per lane; LDS dest is wave-uniform base + lane*16
typedef __attribute__((address_space(3))) unsigned int lds_uint;
typedef const __attribute__((address_space(1))) unsigned int glob_uint;
static __device__ __forceinline__ void gl_lds16(const void* g, void* l) {
    __builtin_amdgcn_global_load_lds((glob_uint*)g, (lds_uint*)l, 16, 0, 0);
}

// meta layout (ints): [0..7] counts, [8..16] offsets, [17] nblk1, [18] g1 tile ctr,
// [19] g2 tile ctr, [20] nblk2, [24..31] scatter cursors,
// [32..111] table1 (e,m0) step 256, [128..271] table2 (e,m0) step 128

// Fused: blocks [0,1024) router (one wave/token); blocks [1024,2048) zero out[].
__global__ __launch_bounds__(256) void moe_router_zero(
    const float* __restrict__ x, const float* __restrict__ gw,
    int* __restrict__ meta, int* __restrict__ tok_idx, float* __restrict__ tok_w,
    float* __restrict__ out)
{
    if (blockIdx.x >= 1024) {
        int b = blockIdx.x - 1024;
        float4 z4 = {0.f, 0.f, 0.f, 0.f};
#pragma unroll
        for (int i = 0; i < 4; ++i)
            ((float4*)out)[(size_t)b * 1024 + i * 256 + threadIdx.x] = z4;
        return;
    }
    int wave = threadIdx.x >> 6;
    int lane = threadIdx.x & 63;
    int t = blockIdx.x * 4 + wave;

    float acc[NEXP];
#pragma unroll
    for (int e = 0; e < NEXP; ++e) acc[e] = 0.f;

    const float4* xr = (const float4*)(x + (size_t)t * CDIM);
#pragma unroll
    for (int it = 0; it < 4; ++it) {
        int c4 = it * 64 + lane;
        float4 xv = xr[c4];
#pragma unroll
        for (int e = 0; e < NEXP; ++e) {
            float4 gv = ((const float4*)(gw + e * CDIM))[c4];
            acc[e] += xv.x * gv.x + xv.y * gv.y + xv.z * gv.z + xv.w * gv.w;
        }
    }
#pragma unroll
    for (int e = 0; e < NEXP; ++e) {
#pragma unroll
        for (int off = 32; off > 0; off >>= 1)
            acc[e] += __shfl_xor(acc[e], off, 64);
    }
    if (lane == 0) {
        int e0 = 0; float v0 = acc[0];
#pragma unroll
        for (int e = 1; e < NEXP; ++e) if (acc[e] > v0) { v0 = acc[e]; e0 = e; }
        int e1 = -1; float v1 = -3.0e38f;
#pragma unroll
        for (int e = 0; e < NEXP; ++e) if (e != e0 && acc[e] > v1) { v1 = acc[e]; e1 = e; }
        float w0 = 1.f / (1.f + __expf(v1 - v0));   // softmax over {v0,v1}
        tok_idx[2 * t] = e0; tok_idx[2 * t + 1] = e1;
        tok_w[2 * t] = w0;  tok_w[2 * t + 1] = 1.f - w0;
        atomicAdd(&meta[e0], 1);
        atomicAdd(&meta[e1], 1);
    }
}

// prefix-sum + two m-block tables (step 256 for gemm1, step 128 for gemm2)
__global__ void moe_scan(int* meta) {
    if (threadIdx.x == 0) {
        int s = 0;
        for (int e = 0; e < NEXP; ++e) { meta[8 + e] = s; s += meta[e]; }
        meta[16] = s;
        int nb1 = 0;
        for (int e = 0; e < NEXP; ++e) {
            int beg = meta[8 + e], end = meta[8 + e] + meta[e];
            for (int m0 = beg; m0 < end; m0 += 256) {
                meta[32 + 2 * nb1] = e;
                meta[33 + 2 * nb1] = m0;
                ++nb1;
            }
        }
        meta[17] = nb1;
        int nb2 = 0;
        for (int e = 0; e < NEXP; ++e) {
            int beg = meta[8 + e], end = meta[8 + e] + meta[e];
            for (int m0 = beg; m0 < end; m0 += 128) {
                meta[128 + 2 * nb2] = e;
                meta[129 + 2 * nb2] = m0;
                ++nb2;
            }
        }
        meta[20] = nb2;
    }
}

__global__ __launch_bounds__(256) void moe_scatter(
    const int* __restrict__ tok_idx, const float* __restrict__ tok_w, int* meta,
    int* __restrict__ pair_token, float* __restrict__ pair_w)
{
    int t = blockIdx.x * 256 + threadIdx.x;
    if (t >= TOKENS) return;
#pragma unroll
    for (int k = 0; k < 2; ++k) {
        int e = tok_idx[2 * t + k];
        int pos = atomicAdd(&meta[24 + e], 1);
        int slot = meta[8 + e] + pos;
        pair_token[slot] = t;
        pair_w[slot] = tok_w[2 * t + k];
    }
}

// Fused: blocks [0,1024) gather Xg rows (8/block); blocks [1024, 1024+5632) conv w1/w2.
__global__ __launch_bounds__(256) void moe_gather_conv12(
    const float* __restrict__ x, const int* __restrict__ pair_token,
    unsigned short* __restrict__ Xg,
    const float* __restrict__ w1, const float* __restrict__ w2,
    unsigned short* __restrict__ w1b, unsigned short* __restrict__ w2b)
{
    if (blockIdx.x < 1024) {
        int base = blockIdx.x * 8;
        int i = threadIdx.x;
#pragma unroll
        for (int r = 0; r < 8; ++r) {
            int row = base + r;
            int t = pair_token[row];
            float4 v = ((const float4*)(x + (size_t)t * CDIM))[i];
            ushort4 o;
            o.x = f2bf(v.x); o.y = f2bf(v.y); o.z = f2bf(v.z); o.w = f2bf(v.w);
            ((ushort4*)(Xg + (size_t)row * CDIM))[i] = o;
        }
        return;
    }
    int zz = blockIdx.x - 1024;            // 0..5631
    int which = zz / 2816;                 // 0: w1, 1: w2
    int rr = zz - which * 2816;
    int e = rr / 352;
    int blk = rr - e * 352;
    const float* wsrc = which ? w2 : w1;
    unsigned short* wdst = which ? w2b : w1b;
    int half = threadIdx.x >> 7;           // 0..1
    int col = (threadIdx.x & 127) * 8;     // 8 bf16 = 16B store
#pragma unroll
    for (int r = 0; r < 4; ++r) {
        int row = blk * 8 + r * 2 + half;
        unsigned short* dst = wdst + ((size_t)e * HPAD2 + row) * CDIM;
        uint4 pv;
        if (row < HDIM) {
            const float* src = wsrc + ((size_t)e * HDIM + row) * CDIM + col;
            float4 a = *(const float4*)(src);
            float4 b = *(const float4*)(src + 4);
            pv.x = pack2(a.x, a.y); pv.y = pack2(a.z, a.w);
            pv.z = pack2(b.x, b.y); pv.w = pack2(b.z, b.w);
        } else {
            pv = uint4{0, 0, 0, 0};
        }
        *(uint4*)(dst + col) = pv;
    }
}

// ---------------- grouped GEMMs ----------------
// LDS row-major [*][64] bf16 with 16B-chunk XOR swizzle (both-sides, rule 21).
#define SWZ(row, ch) (((row) << 6) + ((((ch) ^ ((row) & 7))) << 3))

// GEMM1 (R8 8-phase body, unchanged) + conv_w3 TAIL BACKFILL:
// unified counter: tiles [0, ntile1) are gemm1; [ntile1, ntile1+256) convert w3
// (32 rows/chunk) on CUs idled by gemm1's tail quantization. w3b is consumed
// only by the NEXT dispatch (gemm2), so no intra-kernel ordering is needed.
__global__ __launch_bounds__(512, 2) void moe_gemm1(
    const unsigned short* __restrict__ Xg,
    const unsigned short* __restrict__ w1b, const unsigned short* __restrict__ w2b,
    const float* __restrict__ pair_w, int* __restrict__ meta,
    unsigned short* __restrict__ act,
    const float* __restrict__ w3, unsigned short* __restrict__ w3b)
{
    __shared__ unsigned short sA[2][256 * 64];   // 32 KB x2
    __shared__ unsigned short sB[2][256 * 64];   // 32 KB x2 (rows 0..127 w1, 128..255 w2)
    __shared__ int sTile;

    int tid = threadIdx.x;
    int lane = tid & 63;
    int wv = tid >> 6;               // 0..7
    int wm = wv >> 2, wn = wv & 3;   // 2m x 4n
    int l3 = lane >> 3;
    int l15 = lane & 15, l4 = lane >> 4;
    int srcc = (((lane & 7) ^ l3) << 3);   // pre-swizzled source column (elements)

    int ntile = meta[17] * NTB1;

    for (;;) {
        if (tid == 0) sTile = atomicAdd(&meta[18], 1);
        __syncthreads();
        int t = sTile;
        if (t >= ntile + NCONV3) break;

        if (t >= ntile) {
            // ---- conv_w3 tail chunk: 32 rows, 16 lanes/row x 22 uint4 each ----
            int c = t - ntile;
            int grow = c * 32 + (tid >> 4);          // global row 0..8191 (e*1024 + crow)
            int lanec = tid & 15;
            const float* src = w3 + (size_t)grow * HDIM;
            unsigned short* dst = w3b + (size_t)grow * HPAD2;
#pragma unroll
            for (int k = 0; k < 22; ++k) {
                int h = (lanec + k * 16) * 8;
                uint4 pv;
                if (h + 8 <= HDIM) {
                    float2 a = *(const float2*)(src + h);
                    float2 b = *(const float2*)(src + h + 2);
                    float2 c2 = *(const float2*)(src + h + 4);
                    float2 d = *(const float2*)(src + h + 6);
                    pv.x = pack2(a.x, a.y); pv.y = pack2(b.x, b.y);
                    pv.z = pack2(c2.x, c2.y); pv.w = pack2(d.x, d.y);
                } else if (h < HDIM) {
                    float v[8];
#pragma unroll
                    for (int q = 0; q < 8; ++q) v[q] = (h + q < HDIM) ? src[h + q] : 0.f;
                    pv.x = pack2(v[0], v[1]); pv.y = pack2(v[2], v[3]);
                    pv.z = pack2(v[4], v[5]); pv.w = pack2(v[6], v[7]);
                } else {
                    pv = uint4{0, 0, 0, 0};
                }
                *(uint4*)(dst + h) = pv;
            }
            continue;
        }

        int bm = t / NTB1, bn = t - bm * NTB1;
        int e  = meta[32 + 2 * bm];
        int m0 = meta[33 + 2 * bm];
        int mEnd = meta[9 + e];
        int mEndm1 = mEnd - 1;
        int n0 = bn * 128;

        const unsigned short* w1e = w1b + (size_t)e * HPAD2 * CDIM + (size_t)n0 * CDIM;
        const unsigned short* w2e = w2b + (size_t)e * HPAD2 * CDIM + (size_t)n0 * CDIM;
        const unsigned short* bbase = (wv < 4) ? w1e : w2e;

        f32x4 acc1[8][2], acc2[8][2];
#pragma unroll
        for (int i = 0; i < 8; ++i)
#pragma unroll
            for (int j = 0; j < 2; ++j) {
                acc1[i][j] = {0.f, 0.f, 0.f, 0.f};
                acc2[i][j] = {0.f, 0.f, 0.f, 0.f};
            }

        auto STAGE_A = [&](int b, int kk) {
            int k0 = kk * 64;
#pragma unroll
            for (int i_ = 0; i_ < 4; ++i_) {
                int seg = wv * 4 + i_;
                int arow = seg * 8 + l3;
                int grow = m0 + arow; if (grow > mEndm1) grow = mEndm1;
                gl_lds16(Xg + (size_t)grow * CDIM + k0 + srcc, sA[b] + seg * 512);
            }
        };
        auto STAGE_B = [&](int b, int kk) {
            int k0 = kk * 64;
#pragma unroll
            for (int i_ = 0; i_ < 4; ++i_) {
                int seg = wv * 4 + i_;
                int bseg = (wv < 4) ? seg : seg - 16;
                gl_lds16(bbase + (size_t)(bseg * 8 + l3) * CDIM + k0 + srcc, sB[b] + seg * 512);
            }
        };

        STAGE_A(0, 0); STAGE_B(0, 0);
        STAGE_A(1, 1); STAGE_B(1, 1);          // 16 loads/wave in flight
        asm volatile("s_waitcnt vmcnt(8)" ::: "memory");   // tile0's 8 done
        __builtin_amdgcn_s_barrier();

        for (int t_ = 0; t_ < NT1; ++t_) {
            int cur = t_ & 1;
            const unsigned short* A = sA[cur];
            const unsigned short* B = sB[cur];
            bf16x8 af[2][4], b1f[2][2], b2f[2][2];

            // ---- P0: read af_lo + b1f ; MFMA af_lo x b1 ----
#pragma unroll
            for (int ks = 0; ks < 2; ++ks) {
                int kch = ks * 4 + l4;
#pragma unroll
                for (int i = 0; i < 4; ++i)
                    af[ks][i] = *(const bf16x8*)(A + SWZ(wm * 128 + i * 16 + l15, kch));
#pragma unroll
                for (int j = 0; j < 2; ++j)
                    b1f[ks][j] = *(const bf16x8*)(B + SWZ(wn * 32 + j * 16 + l15, kch));
            }
            __builtin_amdgcn_s_barrier();
            asm volatile("s_waitcnt lgkmcnt(0)" ::: "memory");
            __builtin_amdgcn_s_setprio(1);
#pragma unroll
            for (int ks = 0; ks < 2; ++ks)
#pragma unroll
                for (int i = 0; i < 4; ++i)
#pragma unroll
                    for (int j = 0; j < 2; ++j)
                        acc1[i][j] = __builtin_amdgcn_mfma_f32_16x16x32_bf16(af[ks][i], b1f[ks][j], acc1[i][j], 0, 0, 0);
            __builtin_amdgcn_s_setprio(0);
            __builtin_amdgcn_s_barrier();

            // ---- P1: read b2f ; MFMA af_lo x b2 ----
#pragma unroll
            for (int ks = 0; ks < 2; ++ks) {
                int kch = ks * 4 + l4;
#pragma unroll
                for (int j = 0; j < 2; ++j)
                    b2f[ks][j] = *(const bf16x8*)(B + SWZ(128 + wn * 32 + j * 16 + l15, kch));
            }
            __builtin_amdgcn_s_barrier();
            asm volatile("s_waitcnt lgkmcnt(0)" ::: "memory");
            __builtin_amdgcn_s_setprio(1);
#pragma unroll
            for (int ks = 0; ks < 2; ++ks)
#pragma unroll
                for (int i = 0; i < 4; ++i)
#pragma unroll
                    for (int j = 0; j < 2; ++j)
                        acc2[i][j] = __builtin_amdgcn_mfma_f32_16x16x32_bf16(af[ks][i], b2f[ks][j], acc2[i][j], 0, 0, 0);
            __builtin_amdgcn_s_setprio(0);
            __builtin_amdgcn_s_barrier();

            // ---- P2: read af_hi ; stage B(t+2) ; MFMA af_hi x b1 ----
#pragma unroll
            for (int ks = 0; ks < 2; ++ks) {
                int kch = ks * 4 + l4;
#pragma unroll
                for (int i = 0; i < 4; ++i)
                    af[ks][i] = *(const bf16x8*)(A + SWZ(wm * 128 + 64 + i * 16 + l15, kch));
            }
            if (t_ + 2 < NT1) STAGE_B(cur, t_ + 2);
            __builtin_amdgcn_s_barrier();
            asm volatile("s_waitcnt lgkmcnt(0)" ::: "memory");
            __builtin_amdgcn_s_setprio(1);
#pragma unroll
            for (int ks = 0; ks < 2; ++ks)
#pragma unroll
                for (int i = 0; i < 4; ++i)
#pragma unroll
                    for (int j = 0; j < 2; ++j)
                        acc1[4 + i][j] = __builtin_amdgcn_mfma_f32_16x16x32_bf16(af[ks][i], b1f[ks][j], acc1[4 + i][j], 0, 0, 0);
            __builtin_amdgcn_s_setprio(0);
            __builtin_amdgcn_s_barrier();

            // ---- P3: stage A(t+2) ; counted vmcnt ; MFMA af_hi x b2 ----
            if (t_ + 2 < NT1) {
                STAGE_A(cur, t_ + 2);
                asm volatile("s_waitcnt vmcnt(8)" ::: "memory");   // tile t+1's 8 done
            } else {
                asm volatile("s_waitcnt vmcnt(0)" ::: "memory");
            }
            __builtin_amdgcn_s_barrier();
            __builtin_amdgcn_s_setprio(1);
#pragma unroll
            for (int ks = 0; ks < 2; ++ks)
#pragma unroll
                for (int i = 0; i < 4; ++i)
#pragma unroll
                    for (int j = 0; j < 2; ++j)
                        acc2[4 + i][j] = __builtin_amdgcn_mfma_f32_16x16x32_bf16(af[ks][i], b2f[ks][j], acc2[4 + i][j], 0, 0, 0);
            __builtin_amdgcn_s_setprio(0);
            __builtin_amdgcn_s_barrier();
        }

        // epilogue: act = silu(h1)*h2*pair_w (bf16); register-only
#pragma unroll
        for (int i = 0; i < 8; ++i) {
            int rbase = m0 + wm * 128 + ((i & 3) * 16) + ((i >> 2) * 64) + (l4 << 2);
#pragma unroll
            for (int r = 0; r < 4; ++r) {
                int grow = rbase + r;
                if (grow >= mEnd) continue;
                float pw = pair_w[grow];
                size_t rowoff = (size_t)grow * HPAD2;
#pragma unroll
                for (int j = 0; j < 2; ++j) {
                    int gcol = n0 + wn * 32 + j * 16 + l15;
                    int ai = (i & 3) + ((i >> 2) << 2);
                    float h1 = acc1[ai][j][r], h2 = acc2[ai][j][r];
                    float a = (h1 / (1.f + __expf(-h1))) * h2 * pw;
                    act[rowoff + gcol] = f2bf(a);
                }
            }
        }
    }
}

// GEMM2 (R5 body) + SPLIT-K=2: tile 128m x 128n x 1408k, 512 threads, 8 waves,
// wave 64x32, dbuf. Partials atomicAdd into zeroed out (4 fp32 adds/element;
// rounding-order jitter ~1ulp << 2e-2 threshold). Tail: ~1150 tiles / 512 slots
// -> wall 3 half-tiles instead of 2 full.
__global__ __launch_bounds__(512, 2) void moe_gemm2(
    const unsigned short* __restrict__ act,
    const unsigned short* __restrict__ w3b,
    int* __restrict__ meta, const int* __restrict__ pair_token,
    float* __restrict__ out)
{
    __shared__ unsigned short sA[2][128 * 64];   // 16 KB x2
    __shared__ unsigned short sB[2][128 * 64];   // 16 KB x2
    __shared__ int sTile;

    int tid = threadIdx.x;
    int lane = tid & 63;
    int wv = tid >> 6;
    int wm = wv >> 2, wn = wv & 3;   // 2m x 4n, wave 64m x 32n
    int l3 = lane >> 3;
    int srcc = (((lane & 7) ^ l3) << 3);

    int ntile = meta[20] * NTB2 * 2;   // m-blocks x 8 n-tiles x 2 k-halves

    for (;;) {
        if (tid == 0) sTile = atomicAdd(&meta[19], 1);
        __syncthreads();
        int t = sTile;
        if (t >= ntile) break;

        int bm = t >> 4;               // 16 = NTB2 * 2
        int rem = t & 15;
        int bn = rem >> 1;
        int kh = rem & 1;
        int e  = meta[128 + 2 * bm];
        int m0 = meta[129 + 2 * bm];
        int mEnd = meta[9 + e];
        int mEndm1 = mEnd - 1;
        int n0 = bn * 128;
        int kbase = kh * (HPAD2 / 2);

        const unsigned short* w3e = w3b + (size_t)e * CDIM * HPAD2 + (size_t)n0 * HPAD2;

        f32x4 acc[4][2];
#pragma unroll
        for (int i = 0; i < 4; ++i)
#pragma unroll
            for (int j = 0; j < 2; ++j) acc[i][j] = {0.f, 0.f, 0.f, 0.f};

        auto STAGE = [&](int b, int kk) {
            int k0 = kbase + kk * 64;
#pragma unroll
            for (int i_ = 0; i_ < 2; ++i_) {
                int seg = wv * 2 + i_;
                int row = seg * 8 + l3;
                int grow = m0 + row; if (grow > mEndm1) grow = mEndm1;
                gl_lds16(act + (size_t)grow * HPAD2 + k0 + srcc, sA[b] + seg * 512);
                gl_lds16(w3e + (size_t)row * HPAD2 + k0 + srcc, sB[b] + seg * 512);
            }
        };

        STAGE(0, 0);
        __syncthreads();
        for (int t_ = 0; t_ < NT2H; ++t_) {
            int cur = t_ & 1;
            if (t_ + 1 < NT2H) STAGE(cur ^ 1, t_ + 1);
#pragma unroll
            for (int ks = 0; ks < 2; ++ks) {
                int kch = ks * 4 + (lane >> 4);
                bf16x8 af[4], bf[2];
#pragma unroll
                for (int i = 0; i < 4; ++i) {
                    int r = wm * 64 + i * 16 + (lane & 15);
                    af[i] = *(const bf16x8*)(sA[cur] + SWZ(r, kch));
                }
#pragma unroll
                for (int j = 0; j < 2; ++j) {
                    int r = wn * 32 + j * 16 + (lane & 15);
                    bf[j] = *(const bf16x8*)(sB[cur] + SWZ(r, kch));
                }
#pragma unroll
                for (int i = 0; i < 4; ++i)
#pragma unroll
                    for (int j = 0; j < 2; ++j)
                        acc[i][j] = __builtin_amdgcn_mfma_f32_16x16x32_bf16(af[i], bf[j], acc[i][j], 0, 0, 0);
            }
            __syncthreads();
        }

#pragma unroll
        for (int i = 0; i < 4; ++i) {
            int rbase = m0 + wm * 64 + i * 16 + ((lane >> 4) << 2);
#pragma unroll
            for (int r = 0; r < 4; ++r) {
                int grow = rbase + r;
                if (grow >= mEnd) continue;
                int tok = pair_token[grow];
                float* orow = out + (size_t)tok * CDIM;
#pragma unroll
                for (int j = 0; j < 2; ++j) {
                    int gcol = n0 + wn * 32 + j * 16 + (lane & 15);
                    atomicAdd(orow + gcol, acc[i][j][r]);
                }
            }
        }
    }
}

extern "C" void kernel_launch(void* const* d_in, const int* in_sizes, int n_in,
                              void* d_out, int out_size, void* d_ws, size_t ws_size,
                              hipStream_t stream)
{
    const float* x  = (const float*)d_in[0];
    const float* gw = (const float*)d_in[1];
    const float* w1 = (const float*)d_in[2];
    const float* w2 = (const float*)d_in[3];
    const float* w3 = (const float*)d_in[4];
    float* out = (float*)d_out;

    char* ws = (char*)d_ws;
    size_t off = 0;
    auto alloc = [&](size_t bytes) -> void* {
        off = (off + 255) & ~(size_t)255;
        void* p = ws + off;
        off += bytes;
        return p;
    };
    int*   meta       = (int*)alloc(512 * sizeof(int));
    int*   tok_idx    = (int*)alloc((size_t)NPAIR * sizeof(int));
    float* tok_w      = (float*)alloc((size_t)NPAIR * sizeof(float));
    int*   pair_token = (int*)alloc((size_t)NPAIR * sizeof(int));
    float* pair_w     = (float*)alloc((size_t)NPAIR * sizeof(float));
    unsigned short* Xg  = (unsigned short*)alloc((size_t)NPAIR * CDIM * 2);
    unsigned short* act = (unsigned short*)alloc((size_t)NPAIR * HPAD2 * 2);
    unsigned short* w1b = (unsigned short*)alloc((size_t)NEXP * HPAD2 * CDIM * 2);
    unsigned short* w2b = (unsigned short*)alloc((size_t)NEXP * HPAD2 * CDIM * 2);
    unsigned short* w3b = (unsigned short*)alloc((size_t)NEXP * CDIM * HPAD2 * 2);
    (void)ws_size; (void)in_sizes; (void)n_in; (void)out_size;

    hipMemsetAsync(meta, 0, 512 * sizeof(int), stream);
    moe_router_zero<<<2048, 256, 0, stream>>>(x, gw, meta, tok_idx, tok_w, out);
    moe_scan<<<1, 64, 0, stream>>>(meta);
    moe_scatter<<<TOKENS / 256, 256, 0, stream>>>(tok_idx, tok_w, meta, pair_token, pair_w);
    moe_gather_conv12<<<1024 + 5632, 256, 0, stream>>>(x, pair_token, Xg, w1, w2, w1b, w2b);
    moe_gemm1<<<256, 512, 0, stream>>>(Xg, w1b, w2b, pair_w, meta, act, w3, w3b);
    moe_gemm2<<<512, 512, 0, stream>>>(act, w3b, meta, pair_token, out);
}

// Round 13
// 507.544 us; speedup vs baseline: 1.0376x; 1.0376x over previous
//
#include <hip/hip_runtime.h>
#include <hip/hip_bf16.h>
#include <cstdint>
#include <cstddef>

// Problem constants
#define TOKENS 4096       // B*T = 2*2048
#define CDIM   1024
#define HDIM   2730
#define HPAD2  2816       // HDIM padded to multiple of 128
#define NEXP   8
#define NPAIR  (TOKENS * 2)
#define NTB1   (HPAD2 / 128)   // 22 n-tiles for gemm1 (N-tile 128, dual)
#define NTB2   (CDIM / 256)    // 4 n-tiles for gemm2 (N-tile 256)
#define NT1    (CDIM / 64)     // 16 K-steps gemm1
#define NT2    (HPAD2 / 64)    // 44 K-steps gemm2
#define NCONV3 256             // conv_w3 tail chunks in gemm1 (32 rows each)

typedef __bf16 bf16_t;
typedef bf16_t bf16x8 __attribute__((ext_vector_type(8)));
typedef float  f32x4  __attribute__((ext_vector_type(4)));

// fp32 -> bf16, round-to-nearest-even
static __device__ __forceinline__ unsigned short f2bf(float f) {
    union { float f; unsigned int u; } v; v.f = f;
    unsigned int u = v.u;
    return (unsigned short)((u + 0x7FFFu + ((u >> 16) & 1u)) >> 16);
}
static __device__ __forceinline__ unsigned int pack2(float a, float b) {
    return (unsigned int)f2bf(a) | ((unsigned int)f2bf(b) << 16);
}

// async global->LDS, 16B per lane; LDS dest is wave-uniform base + lane*16
typedef __attribute__((address_space(3))) unsigned int lds_uint;
typedef const __attribute__((address_space(1))) unsigned int glob_uint;
static __device__ __forceinline__ void gl_lds16(const void* g, void* l) {
    __builtin_amdgcn_global_load_lds((glob_uint*)g, (lds_uint*)l, 16, 0, 0);
}

// meta layout (ints): [0..7] counts, [8..16] offsets, [17] nblk1, [18] g1 tile ctr,
// [19] g2 tile ctr, [20] nblk2, [24..31] scatter cursors,
// [32..111] table1 (e,m0) step 256 (shared by gemm1 and gemm2), [128..271] table2 (unused)

// Fused: blocks [0,1024) router (one wave/token); blocks [1024,2048) zero out[].
__global__ __launch_bounds__(256) void moe_router_zero(
    const float* __restrict__ x, const float* __restrict__ gw,
    int* __restrict__ meta, int* __restrict__ tok_idx, float* __restrict__ tok_w,
    float* __restrict__ out)
{
    if (blockIdx.x >= 1024) {
        int b = blockIdx.x - 1024;
        float4 z4 = {0.f, 0.f, 0.f, 0.f};
#pragma unroll
        for (int i = 0; i < 4; ++i)
            ((float4*)out)[(size_t)b * 1024 + i * 256 + threadIdx.x] = z4;
        return;
    }
    int wave = threadIdx.x >> 6;
    int lane = threadIdx.x & 63;
    int t = blockIdx.x * 4 + wave;

    float acc[NEXP];
#pragma unroll
    for (int e = 0; e < NEXP; ++e) acc[e] = 0.f;

    const float4* xr = (const float4*)(x + (size_t)t * CDIM);
#pragma unroll
    for (int it = 0; it < 4; ++it) {
        int c4 = it * 64 + lane;
        float4 xv = xr[c4];
#pragma unroll
        for (int e = 0; e < NEXP; ++e) {
            float4 gv = ((const float4*)(gw + e * CDIM))[c4];
            acc[e] += xv.x * gv.x + xv.y * gv.y + xv.z * gv.z + xv.w * gv.w;
        }
    }
#pragma unroll
    for (int e = 0; e < NEXP; ++e) {
#pragma unroll
        for (int off = 32; off > 0; off >>= 1)
            acc[e] += __shfl_xor(acc[e], off, 64);
    }
    if (lane == 0) {
        int e0 = 0; float v0 = acc[0];
#pragma unroll
        for (int e = 1; e < NEXP; ++e) if (acc[e] > v0) { v0 = acc[e]; e0 = e; }
        int e1 = -1; float v1 = -3.0e38f;
#pragma unroll
        for (int e = 0; e < NEXP; ++e) if (e != e0 && acc[e] > v1) { v1 = acc[e]; e1 = e; }
        float w0 = 1.f / (1.f + __expf(v1 - v0));   // softmax over {v0,v1}
        tok_idx[2 * t] = e0; tok_idx[2 * t + 1] = e1;
        tok_w[2 * t] = w0;  tok_w[2 * t + 1] = 1.f - w0;
        atomicAdd(&meta[e0], 1);
        atomicAdd(&meta[e1], 1);
    }
}

// prefix-sum + m-block table (step 256, shared by both GEMMs)
__global__ void moe_scan(int* meta) {
    if (threadIdx.x == 0) {
        int s = 0;
        for (int e = 0; e < NEXP; ++e) { meta[8 + e] = s; s += meta[e]; }
        meta[16] = s;
        int nb1 = 0;
        for (int e = 0; e < NEXP; ++e) {
            int beg = meta[8 + e], end = meta[8 + e] + meta[e];
            for (int m0 = beg; m0 < end; m0 += 256) {
                meta[32 + 2 * nb1] = e;
                meta[33 + 2 * nb1] = m0;
                ++nb1;
            }
        }
        meta[17] = nb1;
    }
}

__global__ __launch_bounds__(256) void moe_scatter(
    const int* __restrict__ tok_idx, const float* __restrict__ tok_w, int* meta,
    int* __restrict__ pair_token, float* __restrict__ pair_w)
{
    int t = blockIdx.x * 256 + threadIdx.x;
    if (t >= TOKENS) return;
#pragma unroll
    for (int k = 0; k < 2; ++k) {
        int e = tok_idx[2 * t + k];
        int pos = atomicAdd(&meta[24 + e], 1);
        int slot = meta[8 + e] + pos;
        pair_token[slot] = t;
        pair_w[slot] = tok_w[2 * t + k];
    }
}

// Fused: blocks [0,1024) gather Xg rows (8/block); blocks [1024, 1024+5632) conv w1/w2.
__global__ __launch_bounds__(256) void moe_gather_conv12(
    const float* __restrict__ x, const int* __restrict__ pair_token,
    unsigned short* __restrict__ Xg,
    const float* __restrict__ w1, const float* __restrict__ w2,
    unsigned short* __restrict__ w1b, unsigned short* __restrict__ w2b)
{
    if (blockIdx.x < 1024) {
        int base = blockIdx.x * 8;
        int i = threadIdx.x;
#pragma unroll
        for (int r = 0; r < 8; ++r) {
            int row = base + r;
            int t = pair_token[row];
            float4 v = ((const float4*)(x + (size_t)t * CDIM))[i];
            ushort4 o;
            o.x = f2bf(v.x); o.y = f2bf(v.y); o.z = f2bf(v.z); o.w = f2bf(v.w);
            ((ushort4*)(Xg + (size_t)row * CDIM))[i] = o;
        }
        return;
    }
    int zz = blockIdx.x - 1024;            // 0..5631
    int which = zz / 2816;                 // 0: w1, 1: w2
    int rr = zz - which * 2816;
    int e = rr / 352;
    int blk = rr - e * 352;
    const float* wsrc = which ? w2 : w1;
    unsigned short* wdst = which ? w2b : w1b;
    int half = threadIdx.x >> 7;           // 0..1
    int col = (threadIdx.x & 127) * 8;     // 8 bf16 = 16B store
#pragma unroll
    for (int r = 0; r < 4; ++r) {
        int row = blk * 8 + r * 2 + half;
        unsigned short* dst = wdst + ((size_t)e * HPAD2 + row) * CDIM;
        uint4 pv;
        if (row < HDIM) {
            const float* src = wsrc + ((size_t)e * HDIM + row) * CDIM + col;
            float4 a = *(const float4*)(src);
            float4 b = *(const float4*)(src + 4);
            pv.x = pack2(a.x, a.y); pv.y = pack2(a.z, a.w);
            pv.z = pack2(b.x, b.y); pv.w = pack2(b.z, b.w);
        } else {
            pv = uint4{0, 0, 0, 0};
        }
        *(uint4*)(dst + col) = pv;
    }
}

// ---------------- grouped GEMMs ----------------
// LDS row-major [*][64] bf16 with 16B-chunk XOR swizzle (both-sides, rule 21).
#define SWZ(row, ch) (((row) << 6) + ((((ch) ^ ((row) & 7))) << 3))

// GEMM1 (R8 8-phase body, unchanged) + conv_w3 tail backfill.
__global__ __launch_bounds__(512, 2) void moe_gemm1(
    const unsigned short* __restrict__ Xg,
    const unsigned short* __restrict__ w1b, const unsigned short* __restrict__ w2b,
    const float* __restrict__ pair_w, int* __restrict__ meta,
    unsigned short* __restrict__ act,
    const float* __restrict__ w3, unsigned short* __restrict__ w3b)
{
    __shared__ unsigned short sA[2][256 * 64];   // 32 KB x2
    __shared__ unsigned short sB[2][256 * 64];   // 32 KB x2 (rows 0..127 w1, 128..255 w2)
    __shared__ int sTile;

    int tid = threadIdx.x;
    int lane = tid & 63;
    int wv = tid >> 6;               // 0..7
    int wm = wv >> 2, wn = wv & 3;   // 2m x 4n
    int l3 = lane >> 3;
    int l15 = lane & 15, l4 = lane >> 4;
    int srcc = (((lane & 7) ^ l3) << 3);   // pre-swizzled source column (elements)

    int ntile = meta[17] * NTB1;

    for (;;) {
        if (tid == 0) sTile = atomicAdd(&meta[18], 1);
        __syncthreads();
        int t = sTile;
        if (t >= ntile + NCONV3) break;

        if (t >= ntile) {
            // ---- conv_w3 tail chunk: 32 rows, 16 lanes/row x 22 uint4 each ----
            int c = t - ntile;
            int grow = c * 32 + (tid >> 4);          // global row 0..8191 (e*1024 + crow)
            int lanec = tid & 15;
            const float* src = w3 + (size_t)grow * HDIM;
            unsigned short* dst = w3b + (size_t)grow * HPAD2;
#pragma unroll
            for (int k = 0; k < 22; ++k) {
                int h = (lanec + k * 16) * 8;
                uint4 pv;
                if (h + 8 <= HDIM) {
                    float2 a = *(const float2*)(src + h);
                    float2 b = *(const float2*)(src + h + 2);
                    float2 c2 = *(const float2*)(src + h + 4);
                    float2 d = *(const float2*)(src + h + 6);
                    pv.x = pack2(a.x, a.y); pv.y = pack2(b.x, b.y);
                    pv.z = pack2(c2.x, c2.y); pv.w = pack2(d.x, d.y);
                } else if (h < HDIM) {
                    float v[8];
#pragma unroll
                    for (int q = 0; q < 8; ++q) v[q] = (h + q < HDIM) ? src[h + q] : 0.f;
                    pv.x = pack2(v[0], v[1]); pv.y = pack2(v[2], v[3]);
                    pv.z = pack2(v[4], v[5]); pv.w = pack2(v[6], v[7]);
                } else {
                    pv = uint4{0, 0, 0, 0};
                }
                *(uint4*)(dst + h) = pv;
            }
            continue;
        }

        int bm = t / NTB1, bn = t - bm * NTB1;
        int e  = meta[32 + 2 * bm];
        int m0 = meta[33 + 2 * bm];
        int mEnd = meta[9 + e];
        int mEndm1 = mEnd - 1;
        int n0 = bn * 128;

        const unsigned short* w1e = w1b + (size_t)e * HPAD2 * CDIM + (size_t)n0 * CDIM;
        const unsigned short* w2e = w2b + (size_t)e * HPAD2 * CDIM + (size_t)n0 * CDIM;
        const unsigned short* bbase = (wv < 4) ? w1e : w2e;

        f32x4 acc1[8][2], acc2[8][2];
#pragma unroll
        for (int i = 0; i < 8; ++i)
#pragma unroll
            for (int j = 0; j < 2; ++j) {
                acc1[i][j] = {0.f, 0.f, 0.f, 0.f};
                acc2[i][j] = {0.f, 0.f, 0.f, 0.f};
            }

        auto STAGE_A = [&](int b, int kk) {
            int k0 = kk * 64;
#pragma unroll
            for (int i_ = 0; i_ < 4; ++i_) {
                int seg = wv * 4 + i_;
                int arow = seg * 8 + l3;
                int grow = m0 + arow; if (grow > mEndm1) grow = mEndm1;
                gl_lds16(Xg + (size_t)grow * CDIM + k0 + srcc, sA[b] + seg * 512);
            }
        };
        auto STAGE_B = [&](int b, int kk) {
            int k0 = kk * 64;
#pragma unroll
            for (int i_ = 0; i_ < 4; ++i_) {
                int seg = wv * 4 + i_;
                int bseg = (wv < 4) ? seg : seg - 16;
                gl_lds16(bbase + (size_t)(bseg * 8 + l3) * CDIM + k0 + srcc, sB[b] + seg * 512);
            }
        };

        STAGE_A(0, 0); STAGE_B(0, 0);
        STAGE_A(1, 1); STAGE_B(1, 1);          // 16 loads/wave in flight
        asm volatile("s_waitcnt vmcnt(8)" ::: "memory");   // tile0's 8 done
        __builtin_amdgcn_s_barrier();

        for (int t_ = 0; t_ < NT1; ++t_) {
            int cur = t_ & 1;
            const unsigned short* A = sA[cur];
            const unsigned short* B = sB[cur];
            bf16x8 af[2][4], b1f[2][2], b2f[2][2];

            // ---- P0: read af_lo + b1f ; MFMA af_lo x b1 ----
#pragma unroll
            for (int ks = 0; ks < 2; ++ks) {
                int kch = ks * 4 + l4;
#pragma unroll
                for (int i = 0; i < 4; ++i)
                    af[ks][i] = *(const bf16x8*)(A + SWZ(wm * 128 + i * 16 + l15, kch));
#pragma unroll
                for (int j = 0; j < 2; ++j)
                    b1f[ks][j] = *(const bf16x8*)(B + SWZ(wn * 32 + j * 16 + l15, kch));
            }
            __builtin_amdgcn_s_barrier();
            asm volatile("s_waitcnt lgkmcnt(0)" ::: "memory");
            __builtin_amdgcn_s_setprio(1);
#pragma unroll
            for (int ks = 0; ks < 2; ++ks)
#pragma unroll
                for (int i = 0; i < 4; ++i)
#pragma unroll
                    for (int j = 0; j < 2; ++j)
                        acc1[i][j] = __builtin_amdgcn_mfma_f32_16x16x32_bf16(af[ks][i], b1f[ks][j], acc1[i][j], 0, 0, 0);
            __builtin_amdgcn_s_setprio(0);
            __builtin_amdgcn_s_barrier();

            // ---- P1: read b2f ; MFMA af_lo x b2 ----
#pragma unroll
            for (int ks = 0; ks < 2; ++ks) {
                int kch = ks * 4 + l4;
#pragma unroll
                for (int j = 0; j < 2; ++j)
                    b2f[ks][j] = *(const bf16x8*)(B + SWZ(128 + wn * 32 + j * 16 + l15, kch));
            }
            __builtin_amdgcn_s_barrier();
            asm volatile("s_waitcnt lgkmcnt(0)" ::: "memory");
            __builtin_amdgcn_s_setprio(1);
#pragma unroll
            for (int ks = 0; ks < 2; ++ks)
#pragma unroll
                for (int i = 0; i < 4; ++i)
#pragma unroll
                    for (int j = 0; j < 2; ++j)
                        acc2[i][j] = __builtin_amdgcn_mfma_f32_16x16x32_bf16(af[ks][i], b2f[ks][j], acc2[i][j], 0, 0, 0);
            __builtin_amdgcn_s_setprio(0);
            __builtin_amdgcn_s_barrier();

            // ---- P2: read af_hi ; stage B(t+2) ; MFMA af_hi x b1 ----
#pragma unroll
            for (int ks = 0; ks < 2; ++ks) {
                int kch = ks * 4 + l4;
#pragma unroll
                for (int i = 0; i < 4; ++i)
                    af[ks][i] = *(const bf16x8*)(A + SWZ(wm * 128 + 64 + i * 16 + l15, kch));
            }
            if (t_ + 2 < NT1) STAGE_B(cur, t_ + 2);
            __builtin_amdgcn_s_barrier();
            asm volatile("s_waitcnt lgkmcnt(0)" ::: "memory");
            __builtin_amdgcn_s_setprio(1);
#pragma unroll
            for (int ks = 0; ks < 2; ++ks)
#pragma unroll
                for (int i = 0; i < 4; ++i)
#pragma unroll
                    for (int j = 0; j < 2; ++j)
                        acc1[4 + i][j] = __builtin_amdgcn_mfma_f32_16x16x32_bf16(af[ks][i], b1f[ks][j], acc1[4 + i][j], 0, 0, 0);
            __builtin_amdgcn_s_setprio(0);
            __builtin_amdgcn_s_barrier();

            // ---- P3: stage A(t+2) ; counted vmcnt ; MFMA af_hi x b2 ----
            if (t_ + 2 < NT1) {
                STAGE_A(cur, t_ + 2);
                asm volatile("s_waitcnt vmcnt(8)" ::: "memory");   // tile t+1's 8 done
            } else {
                asm volatile("s_waitcnt vmcnt(0)" ::: "memory");
            }
            __builtin_amdgcn_s_barrier();
            __builtin_amdgcn_s_setprio(1);
#pragma unroll
            for (int ks = 0; ks < 2; ++ks)
#pragma unroll
                for (int i = 0; i < 4; ++i)
#pragma unroll
                    for (int j = 0; j < 2; ++j)
                        acc2[4 + i][j] = __builtin_amdgcn_mfma_f32_16x16x32_bf16(af[ks][i], b2f[ks][j], acc2[4 + i][j], 0, 0, 0);
            __builtin_amdgcn_s_setprio(0);
            __builtin_amdgcn_s_barrier();
        }

        // epilogue: act = silu(h1)*h2*pair_w (bf16); register-only
#pragma unroll
        for (int i = 0; i < 8; ++i) {
            int rbase = m0 + wm * 128 + ((i & 3) * 16) + ((i >> 2) * 64) + (l4 << 2);
#pragma unroll
            for (int r = 0; r < 4; ++r) {
                int grow = rbase + r;
                if (grow >= mEnd) continue;
                float pw = pair_w[grow];
                size_t rowoff = (size_t)grow * HPAD2;
#pragma unroll
                for (int j = 0; j < 2; ++j) {
                    int gcol = n0 + wn * 32 + j * 16 + l15;
                    int ai = (i & 3) + ((i >> 2) << 2);
                    float h1 = acc1[ai][j][r], h2 = acc2[ai][j][r];
                    float a = (h1 / (1.f + __expf(-h1))) * h2 * pw;
                    act[rowoff + gcol] = f2bf(a);
                }
            }
        }
    }
}

// GEMM2 (NEW 256x256 tile): halves staged bytes (738 -> 369 MB, the measured
// bandwidth bound). 512 threads, 8 waves (2m x 4n), wave 128m x 64n, acc[8][4]
// (= gemm1's proven 128-reg budget), dbuf 128 KB LDS, R5 2-phase body.
// Uses the step-256 table1. out[token] += act * w3b^T via 2 atomicAdds/element.
__global__ __launch_bounds__(512, 2) void moe_gemm2(
    const unsigned short* __restrict__ act,
    const unsigned short* __restrict__ w3b,
    int* __restrict__ meta, const int* __restrict__ pair_token,
    float* __restrict__ out)
{
    __shared__ unsigned short sA[2][256 * 64];   // 32 KB x2
    __shared__ unsigned short sB[2][256 * 64];   // 32 KB x2
    __shared__ int sTile;

    int tid = threadIdx.x;
    int lane = tid & 63;
    int wv = tid >> 6;               // 0..7
    int wm = wv >> 2, wn = wv & 3;   // 2m x 4n, wave 128m x 64n
    int l3 = lane >> 3;
    int l15 = lane & 15, l4 = lane >> 4;
    int srcc = (((lane & 7) ^ l3) << 3);

    int ntile = meta[17] * NTB2;     // step-256 m-blocks x 4 n-tiles

    for (;;) {
        if (tid == 0) sTile = atomicAdd(&meta[19], 1);
        __syncthreads();
        int t = sTile;
        if (t >= ntile) break;

        int bm = t >> 2, bn = t & 3;
        int e  = meta[32 + 2 * bm];
        int m0 = meta[33 + 2 * bm];
        int mEnd = meta[9 + e];
        int mEndm1 = mEnd - 1;
        int n0 = bn * 256;

        const unsigned short* w3e = w3b + (size_t)e * CDIM * HPAD2 + (size_t)n0 * HPAD2;

        f32x4 acc[8][4];
#pragma unroll
        for (int i = 0; i < 8; ++i)
#pragma unroll
            for (int j = 0; j < 4; ++j) acc[i][j] = {0.f, 0.f, 0.f, 0.f};

        auto STAGE = [&](int b, int kk) {
            int k0 = kk * 64;
#pragma unroll
            for (int i_ = 0; i_ < 4; ++i_) {
                int seg = wv * 4 + i_;
                int row = seg * 8 + l3;                 // 0..255
                int grow = m0 + row; if (grow > mEndm1) grow = mEndm1;
                gl_lds16(act + (size_t)grow * HPAD2 + k0 + srcc, sA[b] + seg * 512);
                gl_lds16(w3e + (size_t)row * HPAD2 + k0 + srcc, sB[b] + seg * 512);
            }
        };

        STAGE(0, 0);
        __syncthreads();
        for (int t_ = 0; t_ < NT2; ++t_) {
            int cur = t_ & 1;
            if (t_ + 1 < NT2) STAGE(cur ^ 1, t_ + 1);
#pragma unroll
            for (int ks = 0; ks < 2; ++ks) {
                int kch = ks * 4 + l4;
                bf16x8 af[8], bf[4];
#pragma unroll
                for (int i = 0; i < 8; ++i)
                    af[i] = *(const bf16x8*)(sA[cur] + SWZ(wm * 128 + i * 16 + l15, kch));
#pragma unroll
                for (int j = 0; j < 4; ++j)
                    bf[j] = *(const bf16x8*)(sB[cur] + SWZ(wn * 64 + j * 16 + l15, kch));
#pragma unroll
                for (int i = 0; i < 8; ++i)
#pragma unroll
                    for (int j = 0; j < 4; ++j)
                        acc[i][j] = __builtin_amdgcn_mfma_f32_16x16x32_bf16(af[i], bf[j], acc[i][j], 0, 0, 0);
            }
            __syncthreads();
        }

#pragma unroll
        for (int i = 0; i < 8; ++i) {
            int rbase = m0 + wm * 128 + i * 16 + (l4 << 2);
#pragma unroll
            for (int r = 0; r < 4; ++r) {
                int grow = rbase + r;
                if (grow >= mEnd) continue;
                int tok = pair_token[grow];
                float* orow = out + (size_t)tok * CDIM;
#pragma unroll
                for (int j = 0; j < 4; ++j) {
                    int gcol = n0 + wn * 64 + j * 16 + l15;
                    atomicAdd(orow + gcol, acc[i][j][r]);
                }
            }
        }
    }
}

extern "C" void kernel_launch(void* const* d_in, const int* in_sizes, int n_in,
                              void* d_out, int out_size, void* d_ws, size_t ws_size,
                              hipStream_t stream)
{
    const float* x  = (const float*)d_in[0];
    const float* gw = (const float*)d_in[1];
    const float* w1 = (const float*)d_in[2];
    const float* w2 = (const float*)d_in[3];
    const float* w3 = (const float*)d_in[4];
    float* out = (float*)d_out;

    char* ws = (char*)d_ws;
    size_t off = 0;
    auto alloc = [&](size_t bytes) -> void* {
        off = (off + 255) & ~(size_t)255;
        void* p = ws + off;
        off += bytes;
        return p;
    };
    int*   meta       = (int*)alloc(512 * sizeof(int));
    int*   tok_idx    = (int*)alloc((size_t)NPAIR * sizeof(int));
    float* tok_w      = (float*)alloc((size_t)NPAIR * sizeof(float));
    int*   pair_token = (int*)alloc((size_t)NPAIR * sizeof(int));
    float* pair_w     = (float*)alloc((size_t)NPAIR * sizeof(float));
    unsigned short* Xg  = (unsigned short*)alloc((size_t)NPAIR * CDIM * 2);
    unsigned short* act = (unsigned short*)alloc((size_t)NPAIR * HPAD2 * 2);
    unsigned short* w1b = (unsigned short*)alloc((size_t)NEXP * HPAD2 * CDIM * 2);
    unsigned short* w2b = (unsigned short*)alloc((size_t)NEXP * HPAD2 * CDIM * 2);
    unsigned short* w3b = (unsigned short*)alloc((size_t)NEXP * CDIM * HPAD2 * 2);
    (void)ws_size; (void)in_sizes; (void)n_in; (void)out_size;

    hipMemsetAsync(meta, 0, 512 * sizeof(int), stream);
    moe_router_zero<<<2048, 256, 0, stream>>>(x, gw, meta, tok_idx, tok_w, out);
    moe_scan<<<1, 64, 0, stream>>>(meta);
    moe_scatter<<<TOKENS / 256, 256, 0, stream>>>(tok_idx, tok_w, meta, pair_token, pair_w);
    moe_gather_conv12<<<1024 + 5632, 256, 0, stream>>>(x, pair_token, Xg, w1, w2, w1b, w2b);
    moe_gemm1<<<256, 512, 0, stream>>>(Xg, w1b, w2b, pair_w, meta, act, w3, w3b);
    moe_gemm2<<<256, 512, 0, stream>>>(act, w3b, meta, pair_token, out);
}